// Round 9
// baseline (223.372 us; speedup 1.0000x reference)
//
#include <hip/hip_runtime.h>
#include <math.h>

// Problem dims (fixed by reference)
#define BDIM 2048
#define ODIM 256
#define IDIM 256
#define NZ   8                      // j-splits
#define JBLK (IDIM / NZ)            // 32 j per block
#define NJQ  (JBLK / 4)             // 8 j-quads
#define ZBASE ((float)(IDIM / NZ))  // 32.0f exactly; per-z share of the +IDIM base

typedef float v2f __attribute__((ext_vector_type(2)));

// out[b,o] = IDIM + C * sum_j 1/(D - 2at*cos(phi0 + x[b,j] + p[o,j]))
//   C = (t^2-1)(1-a^2),  D = 1+(at)^2
// cos(x'+p) = cos x' cos p - sin x' sin p =>
//   den = D + mc*pc + ms*ps,  mc=-2at*cos(phi0+x), ms=2at*sin(phi0+x)
//
// R18: R9 structure EXACT (256thr, 64x64 tile, 4b x 4o, NZ=8, padded As4,
// SP4 pair layout, atomic epilogue) + explicit depth-1 REGISTER PREFETCH
// of the next jq's 8 P-quads. Ledger: t ~= 336/w + LDS_pipe; the 336/w
// term (14-21us) is per-wave {read-burst -> lgkmcnt -> FMA} exposure the
// compiler fails to pipeline (R10: w=8 exposed nearly full serial
// latency; R17: L1-streaming alternative failed). Config space is
// exhausted (every corner >= 30.5 by model, VGPR cliffs + LDS capacity +
// NZ=16 penalty) -> attack ILP at fixed w=16. Fully-unrolled jq loop
// keeps qc/qn rotating buffers statically indexed (reg-allocated, no
// scratch). VGPR ~110-125 under the 128 cliff (launch_bounds(256,4),
// 4 waves/SIMD x 120 = 480 <= 512 pool). A-loads stay demand-issued per
// k-row (hide under previous k's compute). Worst case = R9 par (~73us).

__global__ __launch_bounds__(256, 4)
void photonic_fused(const float* __restrict__ X,   // [BDIM][IDIM]
                    const float* __restrict__ P,   // [ODIM][IDIM]
                    float* __restrict__ Out,       // [BDIM][ODIM] (+= semantics)
                    float phi0, float m2at, float p2at,
                    float Dc, float Cnum) {
    __shared__ float4 As4[64][17];       // 17408 B (slot 16 = pad)
    __shared__ float4 SP4[JBLK][2][16];  // 16384 B

    const int tid = threadIdx.x;
    const int tx  = tid & 15;            // o sub-index
    const int ty  = tid >> 4;            // b sub-index 0..15
    const int o0  = blockIdx.x * 64;
    const int b0  = blockIdx.y * 64;
    const int j0  = blockIdx.z * JBLK;

    // ---- fused prologue: sincos margins straight into f32 LDS ----
    #pragma unroll
    for (int i = 0; i < 2; ++i) {
        const int r  = (tid >> 3) + 32 * i;   // 0..63
        const int jq = tid & 7;               // 0..7
        float s0, c0, s1, c1, s2, c2, s3, c3;

        float4 x = *(const float4*)(X + (size_t)(b0 + r) * IDIM + j0 + 4 * jq);
        __sincosf(phi0 + x.x, &s0, &c0);
        __sincosf(phi0 + x.y, &s1, &c1);
        __sincosf(phi0 + x.z, &s2, &c2);
        __sincosf(phi0 + x.w, &s3, &c3);
        As4[r][2 * jq]     = make_float4(m2at * c0, m2at * c1, m2at * c2, m2at * c3);
        As4[r][2 * jq + 1] = make_float4(p2at * s0, p2at * s1, p2at * s2, p2at * s3);

        float4 pv = *(const float4*)(P + (size_t)(o0 + r) * IDIM + j0 + 4 * jq);
        __sincosf(pv.x, &s0, &c0);
        __sincosf(pv.y, &s1, &c1);
        __sincosf(pv.z, &s2, &c2);
        __sincosf(pv.w, &s3, &c3);
        const int pr  = r >> 5;               // 0/1
        const int hi  = (r >> 4) & 1;         // 0/1
        const int tx_ = r & 15;
        float cs[4] = {c0, c1, c2, c3};
        float ss[4] = {s0, s1, s2, s3};
        #pragma unroll
        for (int jj = 0; jj < 4; ++jj) {
            float* cell = (float*)&SP4[4 * jq + jj][pr][tx_];
            cell[hi]     = cs[jj];
            cell[2 + hi] = ss[jj];
        }
    }
    __syncthreads();

    v2f acc[4][2];
    #pragma unroll
    for (int k = 0; k < 4; ++k) { acc[k][0] = (v2f){0.f, 0.f}; acc[k][1] = (v2f){0.f, 0.f}; }

    const v2f D2 = {Dc, Dc};

    // ---- software-pipelined hot loop: prefetch next jq's P-quads ----
    float4 qc0[4], qc1[4];               // current jq's P operands
    #pragma unroll
    for (int j = 0; j < 4; ++j) {
        qc0[j] = SP4[j][0][tx];
        qc1[j] = SP4[j][1][tx];
    }

    #pragma unroll
    for (int jq = 0; jq < NJQ; ++jq) {
        // issue next jq's 8 P-reads NOW; their latency hides under this
        // jq's 4 k-row compute blocks
        float4 qn0[4], qn1[4];
        if (jq + 1 < NJQ) {
            #pragma unroll
            for (int j = 0; j < 4; ++j) {
                qn0[j] = SP4[4 * (jq + 1) + j][0][tx];
                qn1[j] = SP4[4 * (jq + 1) + j][1][tx];
            }
        }

        #pragma unroll
        for (int k = 0; k < 4; ++k) {
            float4 mc4 = As4[ty + 16 * k][2 * jq];
            float4 ms4 = As4[ty + 16 * k][2 * jq + 1];
            float mcf[4] = {mc4.x, mc4.y, mc4.z, mc4.w};
            float msf[4] = {ms4.x, ms4.y, ms4.z, ms4.w};
            #pragma unroll
            for (int p = 0; p < 2; ++p) {
                const float4* q = (p == 0) ? qc0 : qc1;
                v2f d[4];
                #pragma unroll
                for (int j = 0; j < 4; ++j) {
                    v2f pc = {q[j].x, q[j].y};
                    v2f ps = {q[j].z, q[j].w};
                    v2f t = __builtin_elementwise_fma((v2f){msf[j], msf[j]}, ps, D2);
                    d[j]  = __builtin_elementwise_fma((v2f){mcf[j], mcf[j]}, pc, t);
                }
                // quad-rcp over the 4 j's, vectorized over the o-pair
                v2f p01 = d[0] * d[1], p23 = d[2] * d[3];
                v2f s01 = d[0] + d[1], s23 = d[2] + d[3];
                v2f n = __builtin_elementwise_fma(s01, p23, s23 * p01);
                v2f qq = p01 * p23;
                v2f r = {__builtin_amdgcn_rcpf(qq.x), __builtin_amdgcn_rcpf(qq.y)};
                acc[k][p] = __builtin_elementwise_fma(n, r, acc[k][p]);
            }
        }

        // rotate (static indices, pure register renames after unroll)
        if (jq + 1 < NJQ) {
            #pragma unroll
            for (int j = 0; j < 4; ++j) { qc0[j] = qn0[j]; qc1[j] = qn1[j]; }
        }
    }

    // ---- atomic epilogue: base folded in as +ZBASE per z-plane ----
    #pragma unroll
    for (int k = 0; k < 4; ++k)
        #pragma unroll
        for (int p = 0; p < 2; ++p) {
            int b = b0 + ty + 16 * k;
            int o = o0 + p * 32 + tx;
            unsafeAtomicAdd(&Out[(size_t)b * ODIM + o],      fmaf(Cnum, acc[k][p].x, ZBASE));
            unsafeAtomicAdd(&Out[(size_t)b * ODIM + o + 16], fmaf(Cnum, acc[k][p].y, ZBASE));
        }
}

extern "C" void kernel_launch(void* const* d_in, const int* in_sizes, int n_in,
                              void* d_out, int out_size, void* d_ws, size_t ws_size,
                              hipStream_t stream) {
    const float* X = (const float*)d_in[0];   // input_matrix [2048,256] f32
    const float* P = (const float*)d_in[1];   // phase_offset [256,256] f32
    float* Out = (float*)d_out;               // [2048,256] f32

    const double RADIUS = 5e-6, KAPPA = 0.1, N_EFF = 3.48, LAMBDA = 1.55e-6, LOSS_A = 0.99;
    const double TWO_PI = 6.283185307179586476925286766559;
    const double t  = sqrt(1.0 - KAPPA);
    const double a  = LOSS_A;
    const double at = a * t;
    const double phi0 = fmod(TWO_PI * N_EFF * (TWO_PI * RADIUS) / LAMBDA, TWO_PI);
    const double D    = 1.0 + at * at;
    const double Cnum = (t * t - 1.0) * (1.0 - a * a);   // num - den (constant)

    // 4 o-tiles x 32 b-tiles x 8 j-splits = 1024 blocks of 256 thr (4/CU)
    dim3 grid(ODIM / 64, BDIM / 64, NZ);
    photonic_fused<<<grid, 256, 0, stream>>>(
        X, P, Out,
        (float)phi0, (float)(-2.0 * at), (float)(2.0 * at),
        (float)D, (float)Cnum);
}

// Round 10
// 181.121 us; speedup vs baseline: 1.2333x; 1.2333x over previous
//
#include <hip/hip_runtime.h>
#include <math.h>

// Problem dims (fixed by reference)
#define BDIM 2048
#define ODIM 256
#define IDIM 256
#define NZ   8                      // j-splits
#define JBLK (IDIM / NZ)            // 32 j per block
#define NJQ  (JBLK / 4)             // 8 j-quads
#define ZBASE ((float)(IDIM / NZ))  // 32.0f exactly; per-z share of the +IDIM base

typedef float v2f __attribute__((ext_vector_type(2)));

// out[b,o] = IDIM + C * sum_j 1/(D - 2at*cos(phi0 + x[b,j] + p[o,j]))
//   C = (t^2-1)(1-a^2),  D = 1+(at)^2
// cos(x'+p) = cos x' cos p - sin x' sin p =>
//   den = D + mc*pc + ms*ps,  mc=-2at*cos(phi0+x), ms=2at*sin(phi0+x)
//
// R19: clean retry of R18's depth-1 P-prefetch. R18 failed for a known
// mechanical reason (rule #20): rotating buffers + pointer select defeated
// SROA -> arrays demoted to scratch (VGPR=64, 362MB scratch writes, 175us).
// R19 is rotation-free and fully static: jq processed in PAIRS inside a
// fully-unrolled jp<4 loop with two named buffer sets qa*/qb* (alternation
// by structure, zero copies); compute is a __forceinline__ helper taking
// operand arrays by reference, all indices compile-time after unroll.
// Theory unchanged: kernel is exposed-LDS-latency bound (pipe work ~10us
// LDS + ~5us VALU vs 32us observed at w=16; R10 w=8 exposed full serial
// latency). Prefetching jq+1's 8 P-quads one stage early hides the burst.
// VGPR ~90+32 = ~122 < 128 cliff (launch_bounds(256,4), w=16 kept).
// LDS/grid/epilogue = R9 exact. Worst case = R9 par.

__device__ __forceinline__ void cellblk(const float (&mcf)[4], const float (&msf)[4],
                                        const float4 (&q)[4], v2f D2, v2f &acc) {
    v2f d[4];
    #pragma unroll
    for (int j = 0; j < 4; ++j) {
        v2f pc = {q[j].x, q[j].y};
        v2f ps = {q[j].z, q[j].w};
        v2f t = __builtin_elementwise_fma((v2f){msf[j], msf[j]}, ps, D2);
        d[j]  = __builtin_elementwise_fma((v2f){mcf[j], mcf[j]}, pc, t);
    }
    // quad-rcp over the 4 j's, vectorized over the o-pair
    v2f p01 = d[0] * d[1], p23 = d[2] * d[3];
    v2f s01 = d[0] + d[1], s23 = d[2] + d[3];
    v2f n  = __builtin_elementwise_fma(s01, p23, s23 * p01);
    v2f qq = p01 * p23;
    v2f r  = {__builtin_amdgcn_rcpf(qq.x), __builtin_amdgcn_rcpf(qq.y)};
    acc = __builtin_elementwise_fma(n, r, acc);
}

__global__ __launch_bounds__(256, 4)
void photonic_fused(const float* __restrict__ X,   // [BDIM][IDIM]
                    const float* __restrict__ P,   // [ODIM][IDIM]
                    float* __restrict__ Out,       // [BDIM][ODIM] (+= semantics)
                    float phi0, float m2at, float p2at,
                    float Dc, float Cnum) {
    __shared__ float4 As4[64][17];       // 17408 B (slot 16 = pad)
    __shared__ float4 SP4[JBLK][2][16];  // 16384 B

    const int tid = threadIdx.x;
    const int tx  = tid & 15;            // o sub-index
    const int ty  = tid >> 4;            // b sub-index 0..15
    const int o0  = blockIdx.x * 64;
    const int b0  = blockIdx.y * 64;
    const int j0  = blockIdx.z * JBLK;

    // ---- fused prologue: sincos margins straight into f32 LDS ----
    #pragma unroll
    for (int i = 0; i < 2; ++i) {
        const int r  = (tid >> 3) + 32 * i;   // 0..63
        const int jq = tid & 7;               // 0..7
        float s0, c0, s1, c1, s2, c2, s3, c3;

        float4 x = *(const float4*)(X + (size_t)(b0 + r) * IDIM + j0 + 4 * jq);
        __sincosf(phi0 + x.x, &s0, &c0);
        __sincosf(phi0 + x.y, &s1, &c1);
        __sincosf(phi0 + x.z, &s2, &c2);
        __sincosf(phi0 + x.w, &s3, &c3);
        As4[r][2 * jq]     = make_float4(m2at * c0, m2at * c1, m2at * c2, m2at * c3);
        As4[r][2 * jq + 1] = make_float4(p2at * s0, p2at * s1, p2at * s2, p2at * s3);

        float4 pv = *(const float4*)(P + (size_t)(o0 + r) * IDIM + j0 + 4 * jq);
        __sincosf(pv.x, &s0, &c0);
        __sincosf(pv.y, &s1, &c1);
        __sincosf(pv.z, &s2, &c2);
        __sincosf(pv.w, &s3, &c3);
        const int pr  = r >> 5;               // 0/1
        const int hi  = (r >> 4) & 1;         // 0/1
        const int tx_ = r & 15;
        float cs[4] = {c0, c1, c2, c3};
        float ss[4] = {s0, s1, s2, s3};
        #pragma unroll
        for (int jj = 0; jj < 4; ++jj) {
            float* cell = (float*)&SP4[4 * jq + jj][pr][tx_];
            cell[hi]     = cs[jj];
            cell[2 + hi] = ss[jj];
        }
    }
    __syncthreads();

    v2f acc[4][2];
    #pragma unroll
    for (int k = 0; k < 4; ++k) { acc[k][0] = (v2f){0.f, 0.f}; acc[k][1] = (v2f){0.f, 0.f}; }

    const v2f D2 = {Dc, Dc};

    // ---- software-pipelined hot loop: jq pairs, two static buffer sets ----
    float4 qa0[4], qa1[4], qb0[4], qb1[4];
    #pragma unroll
    for (int j = 0; j < 4; ++j) { qa0[j] = SP4[j][0][tx]; qa1[j] = SP4[j][1][tx]; }

    #pragma unroll
    for (int jp = 0; jp < NJQ / 2; ++jp) {
        const int jqA = 2 * jp, jqB = 2 * jp + 1;

        // prefetch jqB's P operands (latency hides under jqA's compute)
        #pragma unroll
        for (int j = 0; j < 4; ++j) {
            qb0[j] = SP4[4 * jqB + j][0][tx];
            qb1[j] = SP4[4 * jqB + j][1][tx];
        }

        #pragma unroll
        for (int k = 0; k < 4; ++k) {
            float4 mc4 = As4[ty + 16 * k][2 * jqA];
            float4 ms4 = As4[ty + 16 * k][2 * jqA + 1];
            const float mcf[4] = {mc4.x, mc4.y, mc4.z, mc4.w};
            const float msf[4] = {ms4.x, ms4.y, ms4.z, ms4.w};
            cellblk(mcf, msf, qa0, D2, acc[k][0]);
            cellblk(mcf, msf, qa1, D2, acc[k][1]);
        }

        // prefetch next pair's first jq (latency hides under jqB's compute)
        if (jp < NJQ / 2 - 1) {
            #pragma unroll
            for (int j = 0; j < 4; ++j) {
                qa0[j] = SP4[4 * (jqB + 1) + j][0][tx];
                qa1[j] = SP4[4 * (jqB + 1) + j][1][tx];
            }
        }

        #pragma unroll
        for (int k = 0; k < 4; ++k) {
            float4 mc4 = As4[ty + 16 * k][2 * jqB];
            float4 ms4 = As4[ty + 16 * k][2 * jqB + 1];
            const float mcf[4] = {mc4.x, mc4.y, mc4.z, mc4.w};
            const float msf[4] = {ms4.x, ms4.y, ms4.z, ms4.w};
            cellblk(mcf, msf, qb0, D2, acc[k][0]);
            cellblk(mcf, msf, qb1, D2, acc[k][1]);
        }
    }

    // ---- atomic epilogue: base folded in as +ZBASE per z-plane ----
    #pragma unroll
    for (int k = 0; k < 4; ++k)
        #pragma unroll
        for (int p = 0; p < 2; ++p) {
            int b = b0 + ty + 16 * k;
            int o = o0 + p * 32 + tx;
            unsafeAtomicAdd(&Out[(size_t)b * ODIM + o],      fmaf(Cnum, acc[k][p].x, ZBASE));
            unsafeAtomicAdd(&Out[(size_t)b * ODIM + o + 16], fmaf(Cnum, acc[k][p].y, ZBASE));
        }
}

extern "C" void kernel_launch(void* const* d_in, const int* in_sizes, int n_in,
                              void* d_out, int out_size, void* d_ws, size_t ws_size,
                              hipStream_t stream) {
    const float* X = (const float*)d_in[0];   // input_matrix [2048,256] f32
    const float* P = (const float*)d_in[1];   // phase_offset [256,256] f32
    float* Out = (float*)d_out;               // [2048,256] f32

    const double RADIUS = 5e-6, KAPPA = 0.1, N_EFF = 3.48, LAMBDA = 1.55e-6, LOSS_A = 0.99;
    const double TWO_PI = 6.283185307179586476925286766559;
    const double t  = sqrt(1.0 - KAPPA);
    const double a  = LOSS_A;
    const double at = a * t;
    const double phi0 = fmod(TWO_PI * N_EFF * (TWO_PI * RADIUS) / LAMBDA, TWO_PI);
    const double D    = 1.0 + at * at;
    const double Cnum = (t * t - 1.0) * (1.0 - a * a);   // num - den (constant)

    // 4 o-tiles x 32 b-tiles x 8 j-splits = 1024 blocks of 256 thr (4/CU)
    dim3 grid(ODIM / 64, BDIM / 64, NZ);
    photonic_fused<<<grid, 256, 0, stream>>>(
        X, P, Out,
        (float)phi0, (float)(-2.0 * at), (float)(2.0 * at),
        (float)D, (float)Cnum);
}

// Round 11
// 71.735 us; speedup vs baseline: 3.1139x; 2.5249x over previous
//
#include <hip/hip_runtime.h>
#include <math.h>

// Problem dims (fixed by reference)
#define BDIM 2048
#define ODIM 256
#define IDIM 256
#define NZ   8                      // j-splits
#define JBLK (IDIM / NZ)            // 32 j per block
#define NJQ  (JBLK / 4)             // 8 j-quads
#define ZBASE ((float)(IDIM / NZ))  // 32.0f; per-z share of the +IDIM base

typedef float v2f __attribute__((ext_vector_type(2)));

// out[b,o] = IDIM + C * sum_j 1/(D - 2at*cos(phi0 + x[b,j] + p[o,j]))
//   C = (t^2-1)(1-a^2),  D = 1+(at)^2
// cos(x'+p) = cos x' cos p - sin x' sin p =>
//   den = D + mc*pc + ms*ps,  mc=-2at*cos(phi0+x), ms=2at*sin(phi0+x)
//
// R20 = R13 verbatim (best measured: 71.7us total, ~30.5us kernel).
// Session ledger (kernel-us, after subtracting the fixed ~41us harness
// workspace-poison fill that runs at 82% HBM peak):
//   R9 32 | R10 47 | R11 42 | R12 39 | R13 30.5 | R14 44 | R15 33
//   R16 39 | R17 39 | R18/R19 scratch-spill disasters (131-175us)
// Model: t ~= 336/waves_per_CU + LDS_pipe_term. All reachable corners of
// the config lattice (VGPR cliffs 64/85/102/128, LDS capacity, NZ=16
// atomic penalty ~+11us, block-count >= residency) evaluate >= 30.5.
// ILP attacks on the latency term are compiler-blocked (R18/R19: staging
// arrays demoted to scratch, VGPR pinned at 64); occupancy attacks are
// capacity-blocked (R14/R15); margin-sourcing alternatives lose on TRANS
// (R16) or L1 thrash (R17). R13 is the empirical optimum: 512 thr,
// 64x64 tile, 2b x 4o microtile, NZ=8, launch_bounds(512,6) -> 24
// waves/CU, free LDS bank patterns, 4.2M one-shot atomics (proven free).

__global__ __launch_bounds__(512, 6)
void photonic_fused(const float* __restrict__ X,   // [BDIM][IDIM]
                    const float* __restrict__ P,   // [ODIM][IDIM]
                    float* __restrict__ Out,       // [BDIM][ODIM] (+= semantics)
                    float phi0, float m2at, float p2at,
                    float Dc, float Cnum) {
    __shared__ float4 As4[64][17];       // 17408 B (slot 16 = pad)
    __shared__ float4 SP4[JBLK][2][16];  // 16384 B

    const int tid = threadIdx.x;
    const int tx  = tid & 15;            // o sub-index 0..15
    const int ty  = (tid >> 4) & 15;     // b sub-index 0..15
    const int hf  = tid >> 8;            // k-half 0/1
    const int o0  = blockIdx.x * 64;
    const int b0  = blockIdx.y * 64;
    const int j0  = blockIdx.z * JBLK;

    // ---- fused prologue: one float4 of X and P per thread ----
    {
        const int r  = tid >> 3;         // 0..63 : row (b for X, o for P)
        const int jq = tid & 7;          // 0..7  : j-quad
        float s0, c0, s1, c1, s2, c2, s3, c3;

        float4 x = *(const float4*)(X + (size_t)(b0 + r) * IDIM + j0 + 4 * jq);
        __sincosf(phi0 + x.x, &s0, &c0);
        __sincosf(phi0 + x.y, &s1, &c1);
        __sincosf(phi0 + x.z, &s2, &c2);
        __sincosf(phi0 + x.w, &s3, &c3);
        As4[r][2 * jq]     = make_float4(m2at * c0, m2at * c1, m2at * c2, m2at * c3);
        As4[r][2 * jq + 1] = make_float4(p2at * s0, p2at * s1, p2at * s2, p2at * s3);

        float4 pv = *(const float4*)(P + (size_t)(o0 + r) * IDIM + j0 + 4 * jq);
        __sincosf(pv.x, &s0, &c0);
        __sincosf(pv.y, &s1, &c1);
        __sincosf(pv.z, &s2, &c2);
        __sincosf(pv.w, &s3, &c3);
        const int pr  = r >> 5;          // 0/1
        const int hi  = (r >> 4) & 1;    // 0/1
        const int tx_ = r & 15;
        float cs[4] = {c0, c1, c2, c3};
        float ss[4] = {s0, s1, s2, s3};
        #pragma unroll
        for (int jj = 0; jj < 4; ++jj) {
            float* cell = (float*)&SP4[4 * jq + jj][pr][tx_];
            cell[hi]     = cs[jj];
            cell[2 + hi] = ss[jj];
        }
    }
    __syncthreads();

    v2f acc[2][2];
    #pragma unroll
    for (int k = 0; k < 2; ++k) { acc[k][0] = (v2f){0.f, 0.f}; acc[k][1] = (v2f){0.f, 0.f}; }

    const v2f D2 = {Dc, Dc};

    #pragma unroll 2
    for (int jq = 0; jq < NJQ; ++jq) {
        // P operands for this j-quad: 8 x b128, shared across both k's
        float4 q0[4], q1[4];
        #pragma unroll
        for (int j = 0; j < 4; ++j) {
            q0[j] = SP4[4 * jq + j][0][tx];
            q1[j] = SP4[4 * jq + j][1][tx];
        }
        #pragma unroll
        for (int k = 0; k < 2; ++k) {
            const int row = ty + 16 * (2 * hf + k);
            float4 mc4 = As4[row][2 * jq];
            float4 ms4 = As4[row][2 * jq + 1];
            float mcf[4] = {mc4.x, mc4.y, mc4.z, mc4.w};
            float msf[4] = {ms4.x, ms4.y, ms4.z, ms4.w};
            #pragma unroll
            for (int p = 0; p < 2; ++p) {
                const float4* q = (p == 0) ? q0 : q1;
                v2f d[4];
                #pragma unroll
                for (int j = 0; j < 4; ++j) {
                    v2f pc = {q[j].x, q[j].y};
                    v2f ps = {q[j].z, q[j].w};
                    v2f t = __builtin_elementwise_fma((v2f){msf[j], msf[j]}, ps, D2);
                    d[j]  = __builtin_elementwise_fma((v2f){mcf[j], mcf[j]}, pc, t);
                }
                // quad-rcp over the 4 j's, vectorized over the o-pair
                v2f p01 = d[0] * d[1], p23 = d[2] * d[3];
                v2f s01 = d[0] + d[1], s23 = d[2] + d[3];
                v2f n = __builtin_elementwise_fma(s01, p23, s23 * p01);
                v2f qq = p01 * p23;
                v2f r = {__builtin_amdgcn_rcpf(qq.x), __builtin_amdgcn_rcpf(qq.y)};
                acc[k][p] = __builtin_elementwise_fma(n, r, acc[k][p]);
            }
        }
    }

    // ---- atomic epilogue: base folded in as +ZBASE per z-plane ----
    #pragma unroll
    for (int k = 0; k < 2; ++k)
        #pragma unroll
        for (int p = 0; p < 2; ++p) {
            int b = b0 + ty + 16 * (2 * hf + k);
            int o = o0 + p * 32 + tx;
            unsafeAtomicAdd(&Out[(size_t)b * ODIM + o],      fmaf(Cnum, acc[k][p].x, ZBASE));
            unsafeAtomicAdd(&Out[(size_t)b * ODIM + o + 16], fmaf(Cnum, acc[k][p].y, ZBASE));
        }
}

extern "C" void kernel_launch(void* const* d_in, const int* in_sizes, int n_in,
                              void* d_out, int out_size, void* d_ws, size_t ws_size,
                              hipStream_t stream) {
    const float* X = (const float*)d_in[0];   // input_matrix [2048,256] f32
    const float* P = (const float*)d_in[1];   // phase_offset [256,256] f32
    float* Out = (float*)d_out;               // [2048,256] f32

    const double RADIUS = 5e-6, KAPPA = 0.1, N_EFF = 3.48, LAMBDA = 1.55e-6, LOSS_A = 0.99;
    const double TWO_PI = 6.283185307179586476925286766559;
    const double t  = sqrt(1.0 - KAPPA);
    const double a  = LOSS_A;
    const double at = a * t;
    const double phi0 = fmod(TWO_PI * N_EFF * (TWO_PI * RADIUS) / LAMBDA, TWO_PI);
    const double D    = 1.0 + at * at;
    const double Cnum = (t * t - 1.0) * (1.0 - a * a);   // num - den (constant)

    // 4 o-tiles x 32 b-tiles x 8 j-splits = 1024 blocks of 512 thr (24 waves/CU)
    dim3 grid(ODIM / 64, BDIM / 64, NZ);
    photonic_fused<<<grid, 512, 0, stream>>>(
        X, P, Out,
        (float)phi0, (float)(-2.0 * at), (float)(2.0 * at),
        (float)D, (float)Cnum);
}